// Round 2
// baseline (786.614 us; speedup 1.0000x reference)
//
#include <hip/hip_runtime.h>
#include <math.h>

#define BN_SCALE 0.9999950000374997f

typedef unsigned short u16;
typedef short bfrag8 __attribute__((ext_vector_type(8)));
typedef float floatx4 __attribute__((ext_vector_type(4)));

struct ushort4_t { u16 x, y, z, w; };

__device__ __forceinline__ u16 f2bf(float f) {
  union { float f; unsigned u; } c; c.f = f;
  unsigned r = c.u + 0x7FFFu + ((c.u >> 16) & 1u);
  return (u16)(r >> 16);
}

__device__ __forceinline__ void gload_lds16(const u16* g, u16* l) {
  __builtin_amdgcn_global_load_lds(
      (const __attribute__((address_space(1))) void*)g,
      (__attribute__((address_space(3))) void*)l, 16, 0, 0);
}

__device__ __forceinline__ floatx4 mfma16(bfrag8 a, bfrag8 b, floatx4 c) {
  return __builtin_amdgcn_mfma_f32_16x16x32_bf16(a, b, c, 0, 0, 0);
}

// ---------------- K1: gate = sigmoid(score_embed) (f32 in, f32 out) ----------------
__global__ void k_gate(const float* __restrict__ se, float* __restrict__ gate) {
  int idx = blockIdx.x * 256 + threadIdx.x;
  if (idx < 3 * 192 * 192) {
    float x = se[idx];
    gate[idx] = 1.0f / (1.0f + expf(-x));
  }
}

// ---------------- K2: fc1 GEMM  C[m,dout] = A[m,:] . w1[dout,:] + b1 ----------------
// A rows: memory/features reshaped [9216 rows][n*512 + d], ld=1536 (f32).
// Tile 128x128, BK=64. f32 loads converted to bf16 into LDS.
__global__ __launch_bounds__(256, 1) void k_fc1(
    const float* __restrict__ memin, const float* __restrict__ featin,
    const float* __restrict__ w1, const float* __restrict__ b1,
    u16* __restrict__ qB, u16* __restrict__ kB) {
  __shared__ u16 At[128 * 64];
  __shared__ u16 Bt[128 * 64];
  const int tid = threadIdx.x, lane = tid & 63, wave = tid >> 6;
  const int bz = blockIdx.z, n = bz >> 1, side = bz & 1;
  const int m0 = blockIdx.y * 128, n0 = blockIdx.x * 128;
  const float* A = (side ? featin : memin) + n * 512;   // ld 1536
  const float* B = w1 + (size_t)n * 512 * 512;          // ld 512
  u16* C = (side ? kB : qB) + (size_t)n * 9216 * 512;

  floatx4 acc[4][4];
  for (int i = 0; i < 4; i++)
    for (int j = 0; j < 4; j++) acc[i][j] = (floatx4){0.f, 0.f, 0.f, 0.f};
  const int wr = wave >> 1, wc = wave & 1;
  const int lr = lane & 15, lq = lane >> 4;

  for (int kk = 0; kk < 8; ++kk) {
    const int k0 = kk * 64;
    __syncthreads();
    for (int it = 0; it < 8; ++it) {
      int s = it * 256 + tid;               // float4 index within 128x64 tile
      int row = s >> 4, c4 = (s & 15) << 2;
      float4 av = *(const float4*)&A[(size_t)(m0 + row) * 1536 + k0 + c4];
      ushort4_t ah = {f2bf(av.x), f2bf(av.y), f2bf(av.z), f2bf(av.w)};
      *(ushort4_t*)&At[row * 64 + c4] = ah;
      float4 bv = *(const float4*)&B[(size_t)(n0 + row) * 512 + k0 + c4];
      ushort4_t bh = {f2bf(bv.x), f2bf(bv.y), f2bf(bv.z), f2bf(bv.w)};
      *(ushort4_t*)&Bt[row * 64 + c4] = bh;
    }
    __syncthreads();
    for (int k2 = 0; k2 < 64; k2 += 32) {
      bfrag8 a[4], b[4];
      for (int i = 0; i < 4; i++)
        a[i] = *(const bfrag8*)&At[(wr * 64 + i * 16 + lr) * 64 + k2 + lq * 8];
      for (int j = 0; j < 4; j++)
        b[j] = *(const bfrag8*)&Bt[(wc * 64 + j * 16 + lr) * 64 + k2 + lq * 8];
      for (int i = 0; i < 4; i++)
        for (int j = 0; j < 4; j++) acc[i][j] = mfma16(a[i], b[j], acc[i][j]);
    }
  }
  for (int j = 0; j < 4; j++) {
    int col = n0 + wc * 64 + j * 16 + lr;
    float bias = b1[n * 512 + col];
    for (int i = 0; i < 4; i++) {
      int rbase = m0 + wr * 64 + i * 16 + lq * 4;
      for (int rg = 0; rg < 4; rg++)
        C[(size_t)(rbase + rg) * 512 + col] = f2bf(acc[i][j][rg] + bias);
    }
  }
}

// ---------------- K3: per (n,q,k): gated 192x192 score tile + dual max-pool + bn1 ----
// score[s,t] = key[k,s,:] . query[q,t,:]  (A-side = key rows s, B-side = query rows t)
// pooled[n][p][0][t] = max_s, pooled[n][p][1][s] = max_t;  p = q*48+k
__global__ __launch_bounds__(512, 1) void k_score(
    const u16* __restrict__ qB, const u16* __restrict__ kB,
    const float* __restrict__ gate,
    const float* __restrict__ bn1g, const float* __restrict__ bn1b,
    u16* __restrict__ pooled) {
  __shared__ u16 At[192 * 64];
  __shared__ u16 Bt[192 * 64];
  __shared__ float colL[8][192];
  __shared__ float rowL[4][192];
  const int tid = threadIdx.x, lane = tid & 63, wave = tid >> 6;
  const int kIdx = blockIdx.x, qIdx = blockIdx.y, n = blockIdx.z;
  const u16* A = kB + ((size_t)n * 9216 + kIdx * 192) * 512;
  const u16* Bp = qB + ((size_t)n * 9216 + qIdx * 192) * 512;
  const int ws = wave >> 2, wt = wave & 3;   // 2x4 waves over 96x48 tiles
  const int lr = lane & 15, lq = lane >> 4;

  floatx4 acc[6][3];
  for (int i = 0; i < 6; i++)
    for (int j = 0; j < 3; j++) acc[i][j] = (floatx4){0.f, 0.f, 0.f, 0.f};

  for (int kk = 0; kk < 8; ++kk) {
    const int k0 = kk * 64;
    __syncthreads();
    for (int it = 0; it < 3; ++it) {
      int sb = (wave * 3 + it) * 64;
      int s = sb + lane;
      int row = s >> 3, c8 = (s & 7) << 3;
      gload_lds16(A + (size_t)row * 512 + k0 + c8, &At[sb * 8]);
      gload_lds16(Bp + (size_t)row * 512 + k0 + c8, &Bt[sb * 8]);
    }
    __syncthreads();
    for (int k2 = 0; k2 < 64; k2 += 32) {
      bfrag8 a[6], b[3];
      for (int i = 0; i < 6; i++)
        a[i] = *(const bfrag8*)&At[(ws * 96 + i * 16 + lr) * 64 + k2 + lq * 8];
      for (int j = 0; j < 3; j++)
        b[j] = *(const bfrag8*)&Bt[(wt * 48 + j * 16 + lr) * 64 + k2 + lq * 8];
      for (int i = 0; i < 6; i++)
        for (int j = 0; j < 3; j++) acc[i][j] = mfma16(a[i], b[j], acc[i][j]);
    }
  }

  const float* gaten = gate + (size_t)n * 36864;
  float colp[3], rowp[6][4];
  for (int j = 0; j < 3; j++) colp[j] = -INFINITY;
  for (int i = 0; i < 6; i++)
    for (int rg = 0; rg < 4; rg++) rowp[i][rg] = -INFINITY;
  for (int i = 0; i < 6; i++) {
    for (int j = 0; j < 3; j++) {
      int t = wt * 48 + j * 16 + lr;
      for (int rg = 0; rg < 4; rg++) {
        int s = ws * 96 + i * 16 + lq * 4 + rg;
        float v = acc[i][j][rg] * gaten[s * 192 + t];
        colp[j] = fmaxf(colp[j], v);
        rowp[i][rg] = fmaxf(rowp[i][rg], v);
      }
    }
  }
  for (int j = 0; j < 3; j++) colL[ws * 4 + lq][wt * 48 + j * 16 + lr] = colp[j];
  for (int i = 0; i < 6; i++)
    for (int rg = 0; rg < 4; rg++) {
      float v = rowp[i][rg];
      v = fmaxf(v, __shfl_xor(v, 1));
      v = fmaxf(v, __shfl_xor(v, 2));
      v = fmaxf(v, __shfl_xor(v, 4));
      v = fmaxf(v, __shfl_xor(v, 8));
      if (lr == 0) rowL[wt][ws * 96 + i * 16 + lq * 4 + rg] = v;
    }
  __syncthreads();

  const float g1 = bn1g[n] * BN_SCALE;
  const float bb1 = bn1b[n];
  const size_t p = (size_t)qIdx * 48 + kIdx;
  u16* outp = pooled + ((size_t)n * 2304 + p) * 2 * 192;
  for (int idx = tid; idx < 384; idx += 512) {
    if (idx < 192) {
      int t = idx;
      float m = colL[0][t];
      for (int w = 1; w < 8; w++) m = fmaxf(m, colL[w][t]);
      outp[t] = f2bf(m * g1 + bb1);
    } else {
      int s = idx - 192;
      float m = fmaxf(fmaxf(rowL[0][s], rowL[1][s]), fmaxf(rowL[2][s], rowL[3][s]));
      outp[192 + s] = f2bf(m * g1 + bb1);
    }
  }
}

// ---------------- K4: fused fc2 + bn2 + relu + fc3 (partial over f-chunk) ----------
// rows = pooled[n] [4608][192] (bf16); w2 is f32 (converted in staging).
// r[n][row] += sum_f relu(bn2(x.w2[f]))*w3[f]
__global__ __launch_bounds__(256, 1) void k_mlp(
    const u16* __restrict__ pooled, const float* __restrict__ w2,
    const float* __restrict__ b2, const float* __restrict__ g2,
    const float* __restrict__ bb2, const float* __restrict__ w3,
    float* __restrict__ r) {
  __shared__ u16 Xt[128 * 64];
  __shared__ u16 Wt[128 * 64];
  const int tid = threadIdx.x, lane = tid & 63, wave = tid >> 6;
  const int n = blockIdx.z, row0 = blockIdx.y * 128, f0 = blockIdx.x * 512;
  const u16* X = pooled + ((size_t)n * 4608 + row0) * 192;  // ld 192 bf16
  const float* W = w2 + (size_t)n * 2048 * 192;             // ld 192 f32
  const int wr = wave >> 1, wc = wave & 1;
  const int lr = lane & 15, lq = lane >> 4;
  float rp[4][4];
  for (int i = 0; i < 4; i++)
    for (int rg = 0; rg < 4; rg++) rp[i][rg] = 0.f;

  for (int fs = 0; fs < 4; ++fs) {
    const int fb = f0 + fs * 128;
    floatx4 acc[4][4];
    for (int i = 0; i < 4; i++)
      for (int j = 0; j < 4; j++) acc[i][j] = (floatx4){0.f, 0.f, 0.f, 0.f};
    for (int kk = 0; kk < 3; ++kk) {
      const int k0 = kk * 64;
      __syncthreads();
      // X: bf16 internal buffer, async LDS staging
      for (int it = 0; it < 4; ++it) {
        int sb = (wave * 4 + it) * 64;
        int s = sb + lane;
        int row = s >> 3, c8 = (s & 7) << 3;
        gload_lds16(X + (size_t)row * 192 + k0 + c8, &Xt[sb * 8]);
      }
      // W: f32 -> bf16 convert staging
      for (int it = 0; it < 8; ++it) {
        int s = it * 256 + tid;
        int row = s >> 4, c4 = (s & 15) << 2;
        float4 wv = *(const float4*)&W[(size_t)(fb + row) * 192 + k0 + c4];
        ushort4_t wh = {f2bf(wv.x), f2bf(wv.y), f2bf(wv.z), f2bf(wv.w)};
        *(ushort4_t*)&Wt[row * 64 + c4] = wh;
      }
      __syncthreads();
      for (int k2 = 0; k2 < 64; k2 += 32) {
        bfrag8 a[4], b[4];
        for (int i = 0; i < 4; i++)
          a[i] = *(const bfrag8*)&Xt[(wr * 64 + i * 16 + lr) * 64 + k2 + lq * 8];
        for (int j = 0; j < 4; j++)
          b[j] = *(const bfrag8*)&Wt[(wc * 64 + j * 16 + lr) * 64 + k2 + lq * 8];
        for (int i = 0; i < 4; i++)
          for (int j = 0; j < 4; j++) acc[i][j] = mfma16(a[i], b[j], acc[i][j]);
      }
    }
    for (int j = 0; j < 4; j++) {
      int f = fb + wc * 64 + j * 16 + lr;
      float alpha = g2[n * 2048 + f] * BN_SCALE;
      float beta = b2[n * 2048 + f] * alpha + bb2[n * 2048 + f];
      float w3f = w3[n * 2048 + f];
      for (int i = 0; i < 4; i++)
        for (int rg = 0; rg < 4; rg++) {
          float y = acc[i][j][rg] * alpha + beta;
          y = fmaxf(y, 0.f);
          rp[i][rg] += y * w3f;
        }
    }
  }
  for (int i = 0; i < 4; i++)
    for (int rg = 0; rg < 4; rg++) {
      float v = rp[i][rg];
      v += __shfl_xor(v, 1);
      v += __shfl_xor(v, 2);
      v += __shfl_xor(v, 4);
      v += __shfl_xor(v, 8);
      if (lr == 0) {
        int row = row0 + wr * 64 + i * 16 + lq * 4 + rg;
        atomicAdd(&r[n * 4608 + row], v);
      }
    }
}

// ---------------- K5: pair sum + bn3 + layer sum + final norm -> out[q*48+k] --------
__global__ void k_final(const float* __restrict__ r, const float* __restrict__ b3,
                        const float* __restrict__ g3, const float* __restrict__ bb3,
                        const float* __restrict__ ng, const float* __restrict__ nb,
                        float* __restrict__ out) {
  int p = blockIdx.x * 256 + threadIdx.x;
  if (p >= 2304) return;
  float acc = 0.f;
  for (int n = 0; n < 3; ++n) {
    float z = r[n * 4608 + 2 * p] + r[n * 4608 + 2 * p + 1] + 2.f * b3[n];
    acc += z * (g3[n] * BN_SCALE) + bb3[n];
  }
  out[p] = acc * (ng[0] * BN_SCALE) + nb[0];
}

extern "C" void kernel_launch(void* const* d_in, const int* in_sizes, int n_in,
                              void* d_out, int out_size, void* d_ws, size_t ws_size,
                              hipStream_t stream) {
  const float* memory = (const float*)d_in[0];
  const float* features = (const float*)d_in[1];
  const float* fc1_w = (const float*)d_in[2];
  const float* fc1_b = (const float*)d_in[3];
  const float* se = (const float*)d_in[4];
  const float* bn1_g = (const float*)d_in[5];
  const float* bn1_b = (const float*)d_in[6];
  const float* fc2_w = (const float*)d_in[7];
  const float* fc2_b = (const float*)d_in[8];
  const float* bn2_g = (const float*)d_in[9];
  const float* bn2_b = (const float*)d_in[10];
  const float* fc3_w = (const float*)d_in[11];
  const float* fc3_b = (const float*)d_in[12];
  const float* bn3_g = (const float*)d_in[13];
  const float* bn3_b = (const float*)d_in[14];
  const float* norm_g = (const float*)d_in[15];
  const float* norm_b = (const float*)d_in[16];

  char* ws = (char*)d_ws;
  float* gate = (float*)ws;                                   // 442,368 B
  u16* qB = (u16*)(ws + 442368);                              // 28,311,552 B
  u16* kB = (u16*)(ws + 442368 + 28311552);                   // 28,311,552 B
  u16* pooled = (u16*)(ws + 442368 + 2 * 28311552);           // 5,308,416 B
  float* r = (float*)(ws + 442368 + 2 * 28311552 + 5308416);  // 55,296 B

  hipMemsetAsync(r, 0, 3 * 4608 * sizeof(float), stream);
  k_gate<<<dim3(432), 256, 0, stream>>>(se, gate);
  k_fc1<<<dim3(4, 72, 6), 256, 0, stream>>>(memory, features, fc1_w, fc1_b, qB, kB);
  k_score<<<dim3(48, 48, 3), 512, 0, stream>>>(qB, kB, gate, bn1_g, bn1_b, pooled);
  k_mlp<<<dim3(4, 36, 3), 256, 0, stream>>>(pooled, fc2_w, fc2_b, bn2_g, bn2_b, fc3_w, r);
  k_final<<<dim3(9), 256, 0, stream>>>(r, fc3_b, bn3_g, bn3_b, norm_g, norm_b,
                                       (float*)d_out);
}

// Round 3
// 541.493 us; speedup vs baseline: 1.4527x; 1.4527x over previous
//
#include <hip/hip_runtime.h>
#include <math.h>

#define BN_SCALE 0.9999950000374997f

typedef unsigned short u16;
typedef short bfrag8 __attribute__((ext_vector_type(8)));
typedef float floatx4 __attribute__((ext_vector_type(4)));

struct ushort4_t { u16 x, y, z, w; };

__device__ __forceinline__ u16 f2bf(float f) {
  union { float f; unsigned u; } c; c.f = f;
  unsigned r = c.u + 0x7FFFu + ((c.u >> 16) & 1u);
  return (u16)(r >> 16);
}

__device__ __forceinline__ void gload_lds16(const u16* g, u16* l) {
  __builtin_amdgcn_global_load_lds(
      (const __attribute__((address_space(1))) void*)g,
      (__attribute__((address_space(3))) void*)l, 16, 0, 0);
}

__device__ __forceinline__ floatx4 mfma16(bfrag8 a, bfrag8 b, floatx4 c) {
  return __builtin_amdgcn_mfma_f32_16x16x32_bf16(a, b, c, 0, 0, 0);
}

// ---------------- K1: gate = sigmoid(score_embed) (f32 in, f32 out) ----------------
__global__ void k_gate(const float* __restrict__ se, float* __restrict__ gate) {
  int idx = blockIdx.x * 256 + threadIdx.x;
  if (idx < 3 * 192 * 192) {
    float x = se[idx];
    gate[idx] = 1.0f / (1.0f + expf(-x));
  }
}

// ---------------- K2: fc1 GEMM  C[m,dout] = A[m,:] . w1[dout,:] + b1 ----------------
// A rows: memory/features reshaped [9216 rows][n*512 + d], ld=1536 (f32).
// Tile 128x128, BK=64. Output written in kk-tiled layout:
//   C[n][tile=r/192][kk=c/64][r%192][c%64]   (bf16)
__global__ __launch_bounds__(256, 1) void k_fc1(
    const float* __restrict__ memin, const float* __restrict__ featin,
    const float* __restrict__ w1, const float* __restrict__ b1,
    u16* __restrict__ qB, u16* __restrict__ kB) {
  __shared__ u16 At[128 * 64];
  __shared__ u16 Bt[128 * 64];
  const int tid = threadIdx.x, lane = tid & 63, wave = tid >> 6;
  const int bz = blockIdx.z, n = bz >> 1, side = bz & 1;
  const int m0 = blockIdx.y * 128, n0 = blockIdx.x * 128;
  const float* A = (side ? featin : memin) + n * 512;   // ld 1536
  const float* B = w1 + (size_t)n * 512 * 512;          // ld 512
  u16* C = (side ? kB : qB) + (size_t)n * 9216 * 512;

  floatx4 acc[4][4];
  for (int i = 0; i < 4; i++)
    for (int j = 0; j < 4; j++) acc[i][j] = (floatx4){0.f, 0.f, 0.f, 0.f};
  const int wr = wave >> 1, wc = wave & 1;
  const int lr = lane & 15, lq = lane >> 4;

  for (int kk = 0; kk < 8; ++kk) {
    const int k0 = kk * 64;
    __syncthreads();
    for (int it = 0; it < 8; ++it) {
      int s = it * 256 + tid;               // float4 index within 128x64 tile
      int row = s >> 4, c4 = (s & 15) << 2;
      float4 av = *(const float4*)&A[(size_t)(m0 + row) * 1536 + k0 + c4];
      ushort4_t ah = {f2bf(av.x), f2bf(av.y), f2bf(av.z), f2bf(av.w)};
      *(ushort4_t*)&At[row * 64 + c4] = ah;
      float4 bv = *(const float4*)&B[(size_t)(n0 + row) * 512 + k0 + c4];
      ushort4_t bh = {f2bf(bv.x), f2bf(bv.y), f2bf(bv.z), f2bf(bv.w)};
      *(ushort4_t*)&Bt[row * 64 + c4] = bh;
    }
    __syncthreads();
    for (int k2 = 0; k2 < 64; k2 += 32) {
      bfrag8 a[4], b[4];
      for (int i = 0; i < 4; i++)
        a[i] = *(const bfrag8*)&At[(wr * 64 + i * 16 + lr) * 64 + k2 + lq * 8];
      for (int j = 0; j < 4; j++)
        b[j] = *(const bfrag8*)&Bt[(wc * 64 + j * 16 + lr) * 64 + k2 + lq * 8];
      for (int i = 0; i < 4; i++)
        for (int j = 0; j < 4; j++) acc[i][j] = mfma16(a[i], b[j], acc[i][j]);
    }
  }
  for (int j = 0; j < 4; j++) {
    int col = n0 + wc * 64 + j * 16 + lr;
    float bias = b1[n * 512 + col];
    int ct = col >> 6, cw = col & 63;
    for (int i = 0; i < 4; i++) {
      int rbase = m0 + wr * 64 + i * 16 + lq * 4;
      for (int rg = 0; rg < 4; rg++) {
        int rr = rbase + rg;
        int tile = rr / 192, rw = rr - tile * 192;
        C[(size_t)tile * (192 * 512) + ct * (192 * 64) + rw * 64 + cw] =
            f2bf(acc[i][j][rg] + bias);
      }
    }
  }
}

// ---------------- K3: per (n,q,k): gated 192x192 score tile + dual max-pool + bn1 ----
// 4 waves, each computes a 96x96 sub-tile (acc[6][6]). LDS XOR-swizzled (chunk ^= row&7)
// to kill the 16-way bank conflicts on fragment reads; swizzle is applied on the global
// source side so global_load_lds' fixed lane->slot mapping still gives the right layout.
// Block swizzle: xcd = lin&7 owns k-tiles [6*xcd, 6*xcd+6) -> k-tiles stay L2-resident.
__global__ __launch_bounds__(256, 2) void k_score(
    const u16* __restrict__ qB, const u16* __restrict__ kB,
    const float* __restrict__ gate,
    const float* __restrict__ bn1g, const float* __restrict__ bn1b,
    u16* __restrict__ pooled) {
  __shared__ __align__(16) u16 At[192 * 64];
  __shared__ __align__(16) u16 Bt[192 * 64];
  const int tid = threadIdx.x, lane = tid & 63, wave = tid >> 6;
  const int lin = blockIdx.x, n = blockIdx.y;
  const int xcd = lin & 7, idx = lin >> 3;
  const int qIdx = idx / 6, kIdx = xcd * 6 + (idx - (idx / 6) * 6);
  const u16* A = kB + (size_t)n * 9216 * 512 + (size_t)kIdx * (192 * 512);
  const u16* Bp = qB + (size_t)n * 9216 * 512 + (size_t)qIdx * (192 * 512);
  const int ws = wave >> 1, wt = wave & 1;
  const int lr = lane & 15, lq = lane >> 4;
  const int sw = lr & 7;
  const int cc0 = (lq ^ sw) << 3;        // swizzled u16 col offset, k2=0
  const int cc1 = ((lq + 4) ^ sw) << 3;  // k2=32

  floatx4 acc[6][6];
  for (int i = 0; i < 6; i++)
    for (int j = 0; j < 6; j++) acc[i][j] = (floatx4){0.f, 0.f, 0.f, 0.f};

  for (int kk = 0; kk < 8; ++kk) {
    const u16* Akk = A + kk * (192 * 64);
    const u16* Bkk = Bp + kk * (192 * 64);
    __syncthreads();
    for (int it = 0; it < 6; ++it) {
      int chb = it * 256 + wave * 64;  // wave-uniform chunk base
      int ch = chb + lane;
      int row = ch >> 3, cc = ch & 7;
      int src = (row << 3) + (cc ^ (row & 7));  // swizzled source chunk
      gload_lds16(Akk + src * 8, &At[chb * 8]);
      gload_lds16(Bkk + src * 8, &Bt[chb * 8]);
    }
    __syncthreads();
#pragma unroll
    for (int k2 = 0; k2 < 2; ++k2) {
      const int cco = k2 ? cc1 : cc0;
      bfrag8 a[6], b[6];
      for (int i = 0; i < 6; i++)
        a[i] = *(const bfrag8*)&At[(ws * 96 + i * 16 + lr) * 64 + cco];
      for (int j = 0; j < 6; j++)
        b[j] = *(const bfrag8*)&Bt[(wt * 96 + j * 16 + lr) * 64 + cco];
      for (int i = 0; i < 6; i++)
        for (int j = 0; j < 6; j++) acc[i][j] = mfma16(a[i], b[j], acc[i][j]);
    }
  }

  const float* gaten = gate + (size_t)n * 36864;
  float colp[6], rowp[6][4];
  for (int j = 0; j < 6; j++) colp[j] = -INFINITY;
  for (int i = 0; i < 6; i++)
    for (int rg = 0; rg < 4; rg++) rowp[i][rg] = -INFINITY;
  for (int i = 0; i < 6; i++) {
    for (int j = 0; j < 6; j++) {
      int t = wt * 96 + j * 16 + lr;
      for (int rg = 0; rg < 4; rg++) {
        int s = ws * 96 + i * 16 + lq * 4 + rg;
        float v = acc[i][j][rg] * gaten[s * 192 + t];
        colp[j] = fmaxf(colp[j], v);
        rowp[i][rg] = fmaxf(rowp[i][rg], v);
      }
    }
  }
  __syncthreads();  // all waves done reading At/Bt; reuse as reduction scratch
  float* colL = (float*)At;  // [8][192]
  float* rowL = (float*)Bt;  // [2][192]
  for (int j = 0; j < 6; j++)
    colL[(ws * 4 + lq) * 192 + wt * 96 + j * 16 + lr] = colp[j];
  for (int i = 0; i < 6; i++)
    for (int rg = 0; rg < 4; rg++) {
      float v = rowp[i][rg];
      v = fmaxf(v, __shfl_xor(v, 1));
      v = fmaxf(v, __shfl_xor(v, 2));
      v = fmaxf(v, __shfl_xor(v, 4));
      v = fmaxf(v, __shfl_xor(v, 8));
      if (lr == 0) rowL[wt * 192 + ws * 96 + i * 16 + lq * 4 + rg] = v;
    }
  __syncthreads();

  const float g1 = bn1g[n] * BN_SCALE;
  const float bb1 = bn1b[n];
  u16* outp = pooled + ((size_t)n * 2304 + (size_t)qIdx * 48 + kIdx) * 384;
  for (int id = tid; id < 384; id += 256) {
    if (id < 192) {
      float m = colL[id];
      for (int w = 1; w < 8; w++) m = fmaxf(m, colL[w * 192 + id]);
      outp[id] = f2bf(m * g1 + bb1);
    } else {
      int s = id - 192;
      float m = fmaxf(rowL[s], rowL[192 + s]);
      outp[id] = f2bf(m * g1 + bb1);
    }
  }
}

// ---------------- K4: fused fc2 + bn2 + relu + fc3 (partial over f-chunk) ----------
// rows = pooled[n] [4608][192] (bf16); w2 is f32 (converted in staging).
// r[n][row] += sum_f relu(bn2(x.w2[f]))*w3[f]
__global__ __launch_bounds__(256, 1) void k_mlp(
    const u16* __restrict__ pooled, const float* __restrict__ w2,
    const float* __restrict__ b2, const float* __restrict__ g2,
    const float* __restrict__ bb2, const float* __restrict__ w3,
    float* __restrict__ r) {
  __shared__ u16 Xt[128 * 64];
  __shared__ u16 Wt[128 * 64];
  const int tid = threadIdx.x, lane = tid & 63, wave = tid >> 6;
  const int n = blockIdx.z, row0 = blockIdx.y * 128, f0 = blockIdx.x * 512;
  const u16* X = pooled + ((size_t)n * 4608 + row0) * 192;  // ld 192 bf16
  const float* W = w2 + (size_t)n * 2048 * 192;             // ld 192 f32
  const int wr = wave >> 1, wc = wave & 1;
  const int lr = lane & 15, lq = lane >> 4;
  float rp[4][4];
  for (int i = 0; i < 4; i++)
    for (int rg = 0; rg < 4; rg++) rp[i][rg] = 0.f;

  for (int fs = 0; fs < 4; ++fs) {
    const int fb = f0 + fs * 128;
    floatx4 acc[4][4];
    for (int i = 0; i < 4; i++)
      for (int j = 0; j < 4; j++) acc[i][j] = (floatx4){0.f, 0.f, 0.f, 0.f};
    for (int kk = 0; kk < 3; ++kk) {
      const int k0 = kk * 64;
      __syncthreads();
      // X: bf16 internal buffer, async LDS staging
      for (int it = 0; it < 4; ++it) {
        int sb = (wave * 4 + it) * 64;
        int s = sb + lane;
        int row = s >> 3, c8 = (s & 7) << 3;
        gload_lds16(X + (size_t)row * 192 + k0 + c8, &Xt[sb * 8]);
      }
      // W: f32 -> bf16 convert staging
      for (int it = 0; it < 8; ++it) {
        int s = it * 256 + tid;
        int row = s >> 4, c4 = (s & 15) << 2;
        float4 wv = *(const float4*)&W[(size_t)(fb + row) * 192 + k0 + c4];
        ushort4_t wh = {f2bf(wv.x), f2bf(wv.y), f2bf(wv.z), f2bf(wv.w)};
        *(ushort4_t*)&Wt[row * 64 + c4] = wh;
      }
      __syncthreads();
      for (int k2 = 0; k2 < 64; k2 += 32) {
        bfrag8 a[4], b[4];
        for (int i = 0; i < 4; i++)
          a[i] = *(const bfrag8*)&Xt[(wr * 64 + i * 16 + lr) * 64 + k2 + lq * 8];
        for (int j = 0; j < 4; j++)
          b[j] = *(const bfrag8*)&Wt[(wc * 64 + j * 16 + lr) * 64 + k2 + lq * 8];
        for (int i = 0; i < 4; i++)
          for (int j = 0; j < 4; j++) acc[i][j] = mfma16(a[i], b[j], acc[i][j]);
      }
    }
    for (int j = 0; j < 4; j++) {
      int f = fb + wc * 64 + j * 16 + lr;
      float alpha = g2[n * 2048 + f] * BN_SCALE;
      float beta = b2[n * 2048 + f] * alpha + bb2[n * 2048 + f];
      float w3f = w3[n * 2048 + f];
      for (int i = 0; i < 4; i++)
        for (int rg = 0; rg < 4; rg++) {
          float y = acc[i][j][rg] * alpha + beta;
          y = fmaxf(y, 0.f);
          rp[i][rg] += y * w3f;
        }
    }
  }
  for (int i = 0; i < 4; i++)
    for (int rg = 0; rg < 4; rg++) {
      float v = rp[i][rg];
      v += __shfl_xor(v, 1);
      v += __shfl_xor(v, 2);
      v += __shfl_xor(v, 4);
      v += __shfl_xor(v, 8);
      if (lr == 0) {
        int row = row0 + wr * 64 + i * 16 + lq * 4 + rg;
        atomicAdd(&r[n * 4608 + row], v);
      }
    }
}

// ---------------- K5: pair sum + bn3 + layer sum + final norm -> out[q*48+k] --------
__global__ void k_final(const float* __restrict__ r, const float* __restrict__ b3,
                        const float* __restrict__ g3, const float* __restrict__ bb3,
                        const float* __restrict__ ng, const float* __restrict__ nb,
                        float* __restrict__ out) {
  int p = blockIdx.x * 256 + threadIdx.x;
  if (p >= 2304) return;
  float acc = 0.f;
  for (int n = 0; n < 3; ++n) {
    float z = r[n * 4608 + 2 * p] + r[n * 4608 + 2 * p + 1] + 2.f * b3[n];
    acc += z * (g3[n] * BN_SCALE) + bb3[n];
  }
  out[p] = acc * (ng[0] * BN_SCALE) + nb[0];
}

extern "C" void kernel_launch(void* const* d_in, const int* in_sizes, int n_in,
                              void* d_out, int out_size, void* d_ws, size_t ws_size,
                              hipStream_t stream) {
  const float* memory = (const float*)d_in[0];
  const float* features = (const float*)d_in[1];
  const float* fc1_w = (const float*)d_in[2];
  const float* fc1_b = (const float*)d_in[3];
  const float* se = (const float*)d_in[4];
  const float* bn1_g = (const float*)d_in[5];
  const float* bn1_b = (const float*)d_in[6];
  const float* fc2_w = (const float*)d_in[7];
  const float* fc2_b = (const float*)d_in[8];
  const float* bn2_g = (const float*)d_in[9];
  const float* bn2_b = (const float*)d_in[10];
  const float* fc3_w = (const float*)d_in[11];
  const float* fc3_b = (const float*)d_in[12];
  const float* bn3_g = (const float*)d_in[13];
  const float* bn3_b = (const float*)d_in[14];
  const float* norm_g = (const float*)d_in[15];
  const float* norm_b = (const float*)d_in[16];

  char* ws = (char*)d_ws;
  float* gate = (float*)ws;                                   // 442,368 B
  u16* qB = (u16*)(ws + 442368);                              // 28,311,552 B
  u16* kB = (u16*)(ws + 442368 + 28311552);                   // 28,311,552 B
  u16* pooled = (u16*)(ws + 442368 + 2 * 28311552);           // 5,308,416 B
  float* r = (float*)(ws + 442368 + 2 * 28311552 + 5308416);  // 55,296 B

  hipMemsetAsync(r, 0, 3 * 4608 * sizeof(float), stream);
  k_gate<<<dim3(432), 256, 0, stream>>>(se, gate);
  k_fc1<<<dim3(4, 72, 6), 256, 0, stream>>>(memory, features, fc1_w, fc1_b, qB, kB);
  k_score<<<dim3(2304, 3), 256, 0, stream>>>(qB, kB, gate, bn1_g, bn1_b, pooled);
  k_mlp<<<dim3(4, 36, 3), 256, 0, stream>>>(pooled, fc2_w, fc2_b, bn2_g, bn2_b, fc3_w, r);
  k_final<<<dim3(9), 256, 0, stream>>>(r, fc3_b, bn3_g, bn3_b, norm_g, norm_b,
                                       (float*)d_out);
}